// Round 6
// baseline (1067.706 us; speedup 1.0000x reference)
//
#include <hip/hip_runtime.h>

#define EPSV 1e-5f

// DPP-based full-wave sum (verified correct rounds 2-5).
#define DPP_XADD(v, ctrl)                                                  \
    v += __int_as_float(__builtin_amdgcn_update_dpp(                       \
        0, __float_as_int(v), ctrl, 0xF, 0xF, false))

__device__ __forceinline__ float wave_allsum(float v) {
    DPP_XADD(v, 0x128);   // row_ror:8
    DPP_XADD(v, 0x124);   // row_ror:4
    DPP_XADD(v, 0x122);   // row_ror:2
    DPP_XADD(v, 0x121);   // row_ror:1
    DPP_XADD(v, 0x142);   // row_bcast15
    DPP_XADD(v, 0x143);   // row_bcast31
    return __int_as_float(__builtin_amdgcn_readlane(__float_as_int(v), 63));
}

// ============================================================
// Phase 1: input-to-hidden TCL3D (+LN in/out) for all (t,n).
// (unchanged from round 5 — verified)
// ============================================================
__global__ __launch_bounds__(256) void wx_kernel(
    const float* __restrict__ x,
    const float* __restrict__ Wfa, const float* __restrict__ Wfb,
    const float* __restrict__ Wfc,
    const float* __restrict__ Wba, const float* __restrict__ Wbb,
    const float* __restrict__ Wbc,
    const float* __restrict__ lniw, const float* __restrict__ lnib,
    const float* __restrict__ lnow, const float* __restrict__ lnob,
    float* __restrict__ wxo)
{
    __shared__ float Xs[4096];
    __shared__ float S1[2048];
    __shared__ float S2[1024];
    __shared__ float baS[24], bbS[24], bcS[24];
    __shared__ float red[16];

    const int tid  = threadIdx.x;
    const int wid  = tid >> 6, lane = tid & 63;
    const size_t tb = blockIdx.x;
    const float* xp = x + tb * 4096;

    float s = 0.f, s2 = 0.f;
    for (int i = tid; i < 4096; i += 256) {
        float v = xp[i];
        Xs[i] = v;
        s += v; s2 += v * v;
    }
    if (tid < 24) { baS[tid] = Wba[tid]; bbS[tid] = Wbb[tid]; bcS[tid] = Wbc[tid]; }

    __syncthreads();
    #pragma unroll
    for (int off = 32; off > 0; off >>= 1) {
        s  += __shfl_down(s,  off);
        s2 += __shfl_down(s2, off);
    }
    if (lane == 0) { red[wid] = s; red[8 + wid] = s2; }
    __syncthreads();
    s  = red[0] + red[1] + red[2] + red[3];
    s2 = red[8] + red[9] + red[10] + red[11];
    const float muX = s * (1.f / 4096.f);
    const float rsX = rsqrtf(fmaxf(s2 * (1.f / 4096.f) - muX * muX, 0.f) + EPSV);

    const int qh = __builtin_amdgcn_readfirstlane(tid >> 7);   // 0..1
    const int rh = __builtin_amdgcn_readfirstlane(tid >> 6);   // 0..3

    for (int g = 0; g < 3; ++g) {
        {
            float acc[8] = {0,0,0,0,0,0,0,0};
            const int rest = tid;                      // b*16+c
            const float* lw = lniw + g * 4096;
            const float* lb = lnib + g * 4096;
            #pragma unroll
            for (int m = 0; m < 16; ++m) {
                const float xn = (Xs[m*256 + rest] - muX) * rsX;
                const float xv = fmaf(xn, lw[m*256 + rest], lb[m*256 + rest]);
                #pragma unroll
                for (int p = 0; p < 8; ++p)
                    acc[p] = fmaf(xv, Wfa[(g*16 + m)*8 + p], acc[p]);
            }
            #pragma unroll
            for (int p = 0; p < 8; ++p)
                S1[p*256 + (rest ^ (p << 3))] = acc[p];
        }
        __syncthreads();
        {
            float acc[4] = {0,0,0,0};
            const int rest2 = tid & 127;               // c*8+p
            const int c2 = rest2 >> 3, p2 = rest2 & 7;
            #pragma unroll
            for (int m = 0; m < 16; ++m) {
                const float xv = S1[p2*256 + (((m << 4) | c2) ^ (p2 << 3))];
                #pragma unroll
                for (int j = 0; j < 4; ++j)
                    acc[j] = fmaf(xv, Wfb[(g*16 + m)*8 + qh*4 + j], acc[j]);
            }
            #pragma unroll
            for (int j = 0; j < 4; ++j) {
                const int q = qh*4 + j;
                S2[q*128 + (rest2 ^ (q << 3))] = acc[j];
            }
        }
        __syncthreads();
        float v0, v1; int idx0;
        {
            float acc[2] = {0, 0};
            const int rest3 = tid & 63;                // p*8+q
            const int q3 = rest3 & 7, pp = rest3 >> 3;
            #pragma unroll
            for (int m = 0; m < 16; ++m) {
                const float xv = S2[q3*128 + (((m << 3) | pp) ^ (q3 << 3))];
                #pragma unroll
                for (int j = 0; j < 2; ++j)
                    acc[j] = fmaf(xv, Wfc[(g*16 + m)*8 + rh*2 + j], acc[j]);
            }
            const float bpq = baS[g*8 + pp] * bbS[g*8 + q3];
            v0 = acc[0] + bpq * bcS[g*8 + rh*2 + 0];
            v1 = acc[1] + bpq * bcS[g*8 + rh*2 + 1];
            idx0 = rest3 * 8 + rh * 2;
        }
        float t = v0 + v1, t2 = v0*v0 + v1*v1;
        __syncthreads();
        #pragma unroll
        for (int off = 32; off > 0; off >>= 1) {
            t  += __shfl_down(t,  off);
            t2 += __shfl_down(t2, off);
        }
        if (lane == 0) { red[wid] = t; red[8 + wid] = t2; }
        __syncthreads();
        t  = red[0] + red[1] + red[2] + red[3];
        t2 = red[8] + red[9] + red[10] + red[11];
        const float mu  = t * (1.f / 512.f);
        const float var = fmaxf(t2 * (1.f / 512.f) - mu * mu, 0.f);
        const float rs  = rsqrtf(var + EPSV);
        float* wp = wxo + (tb * 3 + g) * 512;
        const float2 lw2 = *(const float2*)(lnow + g*512 + idx0);
        const float2 lb2 = *(const float2*)(lnob + g*512 + idx0);
        float2 o2;
        o2.x = fmaf((v0 - mu) * rs, lw2.x, lb2.x);
        o2.y = fmaf((v1 - mu) * rs, lw2.y, lb2.y);
        *(float2*)(wp + idx0) = o2;
    }
}

// ============================================================
// Phase 2: sequential GRU scan. One block per sample, 3 waves
// = 3 gates. Chain-minimized step:
//  - COMBINE is SLICED across waves (k 0-2 / 3-5 / 6-7); each
//    wave keeps h_old + own-gate Uh in regs, reads only the 2
//    other gates' Uh for its slice (6 LDS reads).
//  - raw h lives in hS (transposed layout); stage A reads it
//    and computes std(h) moments from the SAME 8 registers
//    (each element read exactly once per wave), folding the
//    LN-in affine into the stage-A FMAs via transposed coeffs.
//  - U-factors via uniform (readfirstlane) addrs -> s_load.
//  - all LDS conflict-free b32 (verified R4/R5); single-buffer
//    UhS (barriers provide the WAR edges); 2 barriers/step.
// ============================================================
__global__ __launch_bounds__(192, 1) void scan_kernel(
    const float* __restrict__ wx,     // [T*B, 3, 512]
    const float* __restrict__ h0,     // [B, 512]
    const float* __restrict__ Ufa, const float* __restrict__ Ufb,
    const float* __restrict__ Ufc,
    const float* __restrict__ Uba, const float* __restrict__ Ubb,
    const float* __restrict__ Ubc,
    const float* __restrict__ lniw, const float* __restrict__ lnib,
    const float* __restrict__ lnow, const float* __restrict__ lnob,
    float* __restrict__ out,          // [T*B, 512]
    int T, int B)
{
    const int n    = blockIdx.x;
    const int tid  = threadIdx.x;
    const int lane = tid & 63;
    const int gu   = __builtin_amdgcn_readfirstlane(tid >> 6);  // wave = gate

    __shared__ float hS[512];         // raw h, transposed layout
    __shared__ float T1S[3][512];
    __shared__ float T2S[3][512];
    __shared__ float UhS[3][512];

    const float* __restrict__ WA = Ufa + gu * 64;   // uniform -> SMEM
    const float* __restrict__ WB = Ufb + gu * 64;
    const float* __restrict__ WC = Ufc + gu * 64;

    // ---- coefficients in regs ----
    // lnwT/lnbT: TRANSPOSED LN-in coeffs for stage-A fold:
    // stage A's m-th read is element (d=m, e=lane>>3, f=lane&7)
    // = flat m*64 + lane.
    float lnwT[8], lnbT[8], low8[8], lob8[8], ubias[8];
    {
        const int p_ = lane >> 3, q_ = lane & 7;
        const float bpq = Uba[gu*8 + p_] * Ubb[gu*8 + q_];
        #pragma unroll
        for (int k = 0; k < 8; ++k) {
            lnwT[k]  = lniw[gu*512 + k*64 + lane];
            lnbT[k]  = lnib[gu*512 + k*64 + lane];
            low8[k]  = lnow[gu*512 + lane*8 + k];
            lob8[k]  = lnob[gu*512 + lane*8 + k];
            ubias[k] = bpq * Ubc[gu*8 + k];
        }
    }

    // ---- conflict-free transposed LDS addressing (verified R4/R5) ----
    int wb[8], rb2[8];
    #pragma unroll
    for (int j = 0; j < 8; ++j) wb[j] = j*64 + (lane ^ (j << 2));
    {
        const int c = lane & 7, r = lane >> 3;
        #pragma unroll
        for (int m = 0; m < 8; ++m)
            rb2[m] = c*64 + (((m << 3) | r) ^ (c << 2));
    }

    float hold[3];     // own slice of h (k = gu*3 + kk)
    float pf[3][3];    // wx prefetch, own slice only
    float uo[8];       // own gate's Uh (post-lnout), full 8

#define LOADWX_SLICE(TT, K0, KN)                                           \
    {                                                                      \
        const float* b_ = wx + ((size_t)(TT) * B + n) * 1536 + lane * 8;   \
        _Pragma("unroll")                                                  \
        for (int gg = 0; gg < 3; ++gg)                                     \
            _Pragma("unroll")                                              \
            for (int kk = 0; kk < (KN); ++kk)                              \
                pf[gg][kk] = b_[gg*512 + (K0) + kk];                       \
    }

    // one combined element: k literal, kk literal, gate-role Uh exprs
#define CMB(K, KK, E_UR, E_UZ, E_UN)                                       \
    {                                                                      \
        const float ur_ = (E_UR), uz_ = (E_UZ), un_ = (E_UN);              \
        const float er_ = __expf(-(pf[0][KK] + ur_));                      \
        const float r_  = __builtin_amdgcn_rcpf(1.f + er_);                \
        const float ez_ = __expf(-(pf[1][KK] + uz_));                      \
        const float z_  = __builtin_amdgcn_rcpf(1.f + ez_);                \
        const float e2_ = __expf(2.f * (pf[2][KK] + r_ * un_));            \
        const float nn_ = 1.f - 2.f * __builtin_amdgcn_rcpf(e2_ + 1.f);    \
        const float hn_ = (1.f - z_) * nn_ + z_ * hold[KK];                \
        hold[KK] = hn_;                                                    \
        op_[K]   = hn_;                                                    \
        hS[wb[K]] = hn_;                                                   \
    }

    // ---- prologue: h(0) into hS (slices) + regs + wx(0) prefetch ----
    if (gu == 0) {
        #pragma unroll
        for (int kk = 0; kk < 3; ++kk) {
            hold[kk] = h0[n*512 + lane*8 + kk];
            hS[wb[kk]] = hold[kk];
        }
        LOADWX_SLICE(0, 0, 3)
    } else if (gu == 1) {
        #pragma unroll
        for (int kk = 0; kk < 3; ++kk) {
            hold[kk] = h0[n*512 + lane*8 + 3 + kk];
            hS[wb[3 + kk]] = hold[kk];
        }
        LOADWX_SLICE(0, 3, 3)
    } else {
        #pragma unroll
        for (int kk = 0; kk < 2; ++kk) {
            hold[kk] = h0[n*512 + lane*8 + 6 + kk];
            hS[wb[6 + kk]] = hold[kk];
        }
        LOADWX_SLICE(0, 6, 2)
    }
    __syncthreads();                    // hS(0) ready

    for (int t = 0; t < T; ++t) {
        // ================= PIPELINE: hS -> UhS[gu] (+ uo regs) ========
        {
            float xv[8];
            #pragma unroll
            for (int m = 0; m < 8; ++m) xv[m] = hS[rb2[m]];
            float sA = 0.f, sB = 0.f;
            #pragma unroll
            for (int m = 0; m < 8; ++m) { sA += xv[m]; sB += xv[m]*xv[m]; }
            sA = wave_allsum(sA); sB = wave_allsum(sB);
            const float mu_ = sA * (1.f/512.f);
            const float rs_ = rsqrtf(fmaxf(sB*(1.f/512.f) - mu_*mu_, 0.f)
                                     + EPSV);
            float a_[8] = {0,0,0,0,0,0,0,0};
            #pragma unroll
            for (int m = 0; m < 8; ++m) {
                const float xg = fmaf((xv[m]-mu_)*rs_, lnwT[m], lnbT[m]);
                #pragma unroll
                for (int q = 0; q < 8; ++q)
                    a_[q] = fmaf(xg, WA[m*8 + q], a_[q]);
            }
            #pragma unroll
            for (int k = 0; k < 8; ++k) { T1S[gu][wb[k]] = a_[k]; a_[k] = 0.f; }
            #pragma unroll
            for (int m = 0; m < 8; ++m) {
                const float xv2 = T1S[gu][rb2[m]];
                #pragma unroll
                for (int q = 0; q < 8; ++q)
                    a_[q] = fmaf(xv2, WB[m*8 + q], a_[q]);
            }
            #pragma unroll
            for (int k = 0; k < 8; ++k) { T2S[gu][wb[k]] = a_[k]; a_[k] = 0.f; }
            #pragma unroll
            for (int m = 0; m < 8; ++m) {
                const float xv3 = T2S[gu][rb2[m]];
                #pragma unroll
                for (int q = 0; q < 8; ++q)
                    a_[q] = fmaf(xv3, WC[m*8 + q], a_[q]);
            }
            float sC = 0.f, sD = 0.f;
            #pragma unroll
            for (int k = 0; k < 8; ++k) {
                a_[k] += ubias[k]; sC += a_[k]; sD += a_[k]*a_[k];
            }
            sC = wave_allsum(sC); sD = wave_allsum(sD);
            const float mu2_ = sC * (1.f/512.f);
            const float rs2_ = rsqrtf(fmaxf(sD*(1.f/512.f) - mu2_*mu2_, 0.f)
                                      + EPSV);
            #pragma unroll
            for (int k = 0; k < 8; ++k) {
                uo[k] = fmaf((a_[k]-mu2_)*rs2_, low8[k], lob8[k]);
                UhS[gu][wb[k]] = uo[k];
            }
        }
        __syncthreads();                // UhS (all 3 planes) ready

        // ================= COMBINE (sliced) + h store + prefetch ======
        {
            float* op_ = out + ((size_t)t * B + n) * 512 + lane*8;
            if (gu == 0) {
                CMB(0, 0, uo[0], UhS[1][wb[0]], UhS[2][wb[0]])
                CMB(1, 1, uo[1], UhS[1][wb[1]], UhS[2][wb[1]])
                CMB(2, 2, uo[2], UhS[1][wb[2]], UhS[2][wb[2]])
                if (t + 1 < T) LOADWX_SLICE(t + 1, 0, 3)
            } else if (gu == 1) {
                CMB(3, 0, UhS[0][wb[3]], uo[3], UhS[2][wb[3]])
                CMB(4, 1, UhS[0][wb[4]], uo[4], UhS[2][wb[4]])
                CMB(5, 2, UhS[0][wb[5]], uo[5], UhS[2][wb[5]])
                if (t + 1 < T) LOADWX_SLICE(t + 1, 3, 3)
            } else {
                CMB(6, 0, UhS[0][wb[6]], UhS[1][wb[6]], uo[6])
                CMB(7, 1, UhS[0][wb[7]], UhS[1][wb[7]], uo[7])
                if (t + 1 < T) LOADWX_SLICE(t + 1, 6, 2)
            }
        }
        __syncthreads();                // hS(t+1) ready; UhS WAR edge
    }
#undef LOADWX_SLICE
#undef CMB
}

extern "C" void kernel_launch(void* const* d_in, const int* in_sizes, int n_in,
                              void* d_out, int out_size, void* d_ws, size_t ws_size,
                              hipStream_t stream)
{
    const float* x    = (const float*)d_in[0];
    const float* h0   = (const float*)d_in[1];
    const float* Wfa  = (const float*)d_in[2];
    const float* Wfb  = (const float*)d_in[3];
    const float* Wfc  = (const float*)d_in[4];
    const float* Wba  = (const float*)d_in[5];
    const float* Wbb  = (const float*)d_in[6];
    const float* Wbc  = (const float*)d_in[7];
    const float* Wliw = (const float*)d_in[8];
    const float* Wlib = (const float*)d_in[9];
    const float* Wlow = (const float*)d_in[10];
    const float* Wlob = (const float*)d_in[11];
    const float* Ufa  = (const float*)d_in[12];
    const float* Ufb  = (const float*)d_in[13];
    const float* Ufc  = (const float*)d_in[14];
    const float* Uba  = (const float*)d_in[15];
    const float* Ubb  = (const float*)d_in[16];
    const float* Ubc  = (const float*)d_in[17];
    const float* Uliw = (const float*)d_in[18];
    const float* Ulib = (const float*)d_in[19];
    const float* Ulow = (const float*)d_in[20];
    const float* Ulob = (const float*)d_in[21];

    const int B = in_sizes[1] / 512;            // 16
    const int T = in_sizes[0] / (B * 4096);     // 512

    float* wxws = (float*)d_ws;                 // [T*B, 3, 512] scratch
    float* out  = (float*)d_out;

    wx_kernel<<<T * B, 256, 0, stream>>>(x, Wfa, Wfb, Wfc, Wba, Wbb, Wbc,
                                         Wliw, Wlib, Wlow, Wlob, wxws);
    scan_kernel<<<B, 192, 0, stream>>>(wxws, h0, Ufa, Ufb, Ufc, Uba, Ubb, Ubc,
                                       Uliw, Ulib, Ulow, Ulob, out, T, B);
}

// Round 7
// 951.610 us; speedup vs baseline: 1.1220x; 1.1220x over previous
//
#include <hip/hip_runtime.h>

#define EPSV 1e-5f

// DPP-based full-wave sum (verified correct rounds 2-6).
#define DPP_XADD(v, ctrl)                                                  \
    v += __int_as_float(__builtin_amdgcn_update_dpp(                       \
        0, __float_as_int(v), ctrl, 0xF, 0xF, false))

__device__ __forceinline__ float wave_allsum(float v) {
    DPP_XADD(v, 0x128);   // row_ror:8
    DPP_XADD(v, 0x124);   // row_ror:4
    DPP_XADD(v, 0x122);   // row_ror:2
    DPP_XADD(v, 0x121);   // row_ror:1
    DPP_XADD(v, 0x142);   // row_bcast15
    DPP_XADD(v, 0x143);   // row_bcast31
    return __int_as_float(__builtin_amdgcn_readlane(__float_as_int(v), 63));
}

// LDS-only barrier: waits own wave's DS ops then syncs. Does NOT drain
// vmcnt -> register-destined global loads stay in flight across it.
__device__ __forceinline__ void bar_lds() {
    asm volatile("s_waitcnt lgkmcnt(0)\n\ts_barrier" ::: "memory");
}

// ============================================================
// Phase 1: input-to-hidden TCL3D (+LN in/out) for all (t,n).
// (unchanged from round 5 — verified)
// ============================================================
__global__ __launch_bounds__(256) void wx_kernel(
    const float* __restrict__ x,
    const float* __restrict__ Wfa, const float* __restrict__ Wfb,
    const float* __restrict__ Wfc,
    const float* __restrict__ Wba, const float* __restrict__ Wbb,
    const float* __restrict__ Wbc,
    const float* __restrict__ lniw, const float* __restrict__ lnib,
    const float* __restrict__ lnow, const float* __restrict__ lnob,
    float* __restrict__ wxo)
{
    __shared__ float Xs[4096];
    __shared__ float S1[2048];
    __shared__ float S2[1024];
    __shared__ float baS[24], bbS[24], bcS[24];
    __shared__ float red[16];

    const int tid  = threadIdx.x;
    const int wid  = tid >> 6, lane = tid & 63;
    const size_t tb = blockIdx.x;
    const float* xp = x + tb * 4096;

    float s = 0.f, s2 = 0.f;
    for (int i = tid; i < 4096; i += 256) {
        float v = xp[i];
        Xs[i] = v;
        s += v; s2 += v * v;
    }
    if (tid < 24) { baS[tid] = Wba[tid]; bbS[tid] = Wbb[tid]; bcS[tid] = Wbc[tid]; }

    __syncthreads();
    #pragma unroll
    for (int off = 32; off > 0; off >>= 1) {
        s  += __shfl_down(s,  off);
        s2 += __shfl_down(s2, off);
    }
    if (lane == 0) { red[wid] = s; red[8 + wid] = s2; }
    __syncthreads();
    s  = red[0] + red[1] + red[2] + red[3];
    s2 = red[8] + red[9] + red[10] + red[11];
    const float muX = s * (1.f / 4096.f);
    const float rsX = rsqrtf(fmaxf(s2 * (1.f / 4096.f) - muX * muX, 0.f) + EPSV);

    const int qh = __builtin_amdgcn_readfirstlane(tid >> 7);   // 0..1
    const int rh = __builtin_amdgcn_readfirstlane(tid >> 6);   // 0..3

    for (int g = 0; g < 3; ++g) {
        {
            float acc[8] = {0,0,0,0,0,0,0,0};
            const int rest = tid;                      // b*16+c
            const float* lw = lniw + g * 4096;
            const float* lb = lnib + g * 4096;
            #pragma unroll
            for (int m = 0; m < 16; ++m) {
                const float xn = (Xs[m*256 + rest] - muX) * rsX;
                const float xv = fmaf(xn, lw[m*256 + rest], lb[m*256 + rest]);
                #pragma unroll
                for (int p = 0; p < 8; ++p)
                    acc[p] = fmaf(xv, Wfa[(g*16 + m)*8 + p], acc[p]);
            }
            #pragma unroll
            for (int p = 0; p < 8; ++p)
                S1[p*256 + (rest ^ (p << 3))] = acc[p];
        }
        __syncthreads();
        {
            float acc[4] = {0,0,0,0};
            const int rest2 = tid & 127;               // c*8+p
            const int c2 = rest2 >> 3, p2 = rest2 & 7;
            #pragma unroll
            for (int m = 0; m < 16; ++m) {
                const float xv = S1[p2*256 + (((m << 4) | c2) ^ (p2 << 3))];
                #pragma unroll
                for (int j = 0; j < 4; ++j)
                    acc[j] = fmaf(xv, Wfb[(g*16 + m)*8 + qh*4 + j], acc[j]);
            }
            #pragma unroll
            for (int j = 0; j < 4; ++j) {
                const int q = qh*4 + j;
                S2[q*128 + (rest2 ^ (q << 3))] = acc[j];
            }
        }
        __syncthreads();
        float v0, v1; int idx0;
        {
            float acc[2] = {0, 0};
            const int rest3 = tid & 63;                // p*8+q
            const int q3 = rest3 & 7, pp = rest3 >> 3;
            #pragma unroll
            for (int m = 0; m < 16; ++m) {
                const float xv = S2[q3*128 + (((m << 3) | pp) ^ (q3 << 3))];
                #pragma unroll
                for (int j = 0; j < 2; ++j)
                    acc[j] = fmaf(xv, Wfc[(g*16 + m)*8 + rh*2 + j], acc[j]);
            }
            const float bpq = baS[g*8 + pp] * bbS[g*8 + q3];
            v0 = acc[0] + bpq * bcS[g*8 + rh*2 + 0];
            v1 = acc[1] + bpq * bcS[g*8 + rh*2 + 1];
            idx0 = rest3 * 8 + rh * 2;
        }
        float t = v0 + v1, t2 = v0*v0 + v1*v1;
        __syncthreads();
        #pragma unroll
        for (int off = 32; off > 0; off >>= 1) {
            t  += __shfl_down(t,  off);
            t2 += __shfl_down(t2, off);
        }
        if (lane == 0) { red[wid] = t; red[8 + wid] = t2; }
        __syncthreads();
        t  = red[0] + red[1] + red[2] + red[3];
        t2 = red[8] + red[9] + red[10] + red[11];
        const float mu  = t * (1.f / 512.f);
        const float var = fmaxf(t2 * (1.f / 512.f) - mu * mu, 0.f);
        const float rs  = rsqrtf(var + EPSV);
        float* wp = wxo + (tb * 3 + g) * 512;
        const float2 lw2 = *(const float2*)(lnow + g*512 + idx0);
        const float2 lb2 = *(const float2*)(lnob + g*512 + idx0);
        float2 o2;
        o2.x = fmaf((v0 - mu) * rs, lw2.x, lb2.x);
        o2.y = fmaf((v1 - mu) * rs, lw2.y, lb2.y);
        *(float2*)(wp + idx0) = o2;
    }
}

// ============================================================
// Phase 2: sequential GRU scan — R5 skeleton (1 barrier/step,
// h + own-gate Uh in regs, SMEM weights, conflict-free b32
// LDS) with:
//  - raw LDS-only barrier (no vmcnt drain),
//  - pfA/pfB double-buffered wx prefetch issued right after
//    the barrier (full step of latency slack, never drained),
//  - COMBINE reads only the 2 OTHER gates' Uh planes (16 reads),
//  - loop unrolled x2 so all parities are compile-time.
// ============================================================
__global__ __launch_bounds__(192, 1) void scan_kernel(
    const float* __restrict__ wx,     // [T*B, 3, 512]
    const float* __restrict__ h0,     // [B, 512]
    const float* __restrict__ Ufa, const float* __restrict__ Ufb,
    const float* __restrict__ Ufc,
    const float* __restrict__ Uba, const float* __restrict__ Ubb,
    const float* __restrict__ Ubc,
    const float* __restrict__ lniw, const float* __restrict__ lnib,
    const float* __restrict__ lnow, const float* __restrict__ lnob,
    float* __restrict__ out,          // [T*B, 512]
    int T, int B)
{
    const int n    = blockIdx.x;
    const int tid  = threadIdx.x;
    const int lane = tid & 63;
    const int gu   = __builtin_amdgcn_readfirstlane(tid >> 6);  // wave = gate

    __shared__ float hgS[3][512];
    __shared__ float T1S[3][512];
    __shared__ float T2S[3][512];
    __shared__ float UhS[2][3][512];

    const float* __restrict__ WA = Ufa + gu * 64;   // uniform -> SMEM
    const float* __restrict__ WB = Ufb + gu * 64;
    const float* __restrict__ WC = Ufc + gu * 64;

    // ---- per-element coefficients (lane-varying, stay in VGPRs) ----
    float lnw[8], lnb[8], low8[8], lob8[8], ubias[8];
    {
        const int p_ = lane >> 3, q_ = lane & 7;
        const float bpq = Uba[gu*8 + p_] * Ubb[gu*8 + q_];
        #pragma unroll
        for (int k = 0; k < 8; ++k) {
            lnw[k]   = lniw[gu*512 + lane*8 + k];
            lnb[k]   = lnib[gu*512 + lane*8 + k];
            low8[k]  = lnow[gu*512 + lane*8 + k];
            lob8[k]  = lnob[gu*512 + lane*8 + k];
            ubias[k] = bpq * Ubc[gu*8 + k];
        }
    }

    // ---- conflict-free transposed LDS addressing (verified R4-R6) ----
    int wb[8], rb2[8];
    #pragma unroll
    for (int j = 0; j < 8; ++j) wb[j] = j*64 + (lane ^ (j << 2));
    {
        const int c = lane & 7, r = lane >> 3;
        #pragma unroll
        for (int m = 0; m < 8; ++m)
            rb2[m] = c*64 + (((m << 3) | r) ^ (c << 2));
    }

    // ---- h in regs (element lane*8+k), redundant per wave ----
    float hv[8];
    {
        const float4 a = *(const float4*)(h0 + n*512 + lane*8);
        const float4 b = *(const float4*)(h0 + n*512 + lane*8 + 4);
        hv[0]=a.x; hv[1]=a.y; hv[2]=a.z; hv[3]=a.w;
        hv[4]=b.x; hv[5]=b.y; hv[6]=b.z; hv[7]=b.w;
    }

    float uo[8];                 // own gate's Uh (post-lnout)
    float pfA[3][8], pfB[3][8];  // wx prefetch, double-buffered

#define LOADWX(TT, PF)                                                     \
    {                                                                      \
        const float* base_ = wx + (((size_t)(TT) * B + n) * 3) * 512       \
                             + lane * 8;                                   \
        _Pragma("unroll")                                                  \
        for (int gg = 0; gg < 3; ++gg) {                                   \
            const float4 A_ = *(const float4*)(base_ + gg*512);            \
            const float4 B_ = *(const float4*)(base_ + gg*512 + 4);        \
            PF[gg][0]=A_.x; PF[gg][1]=A_.y; PF[gg][2]=A_.z; PF[gg][3]=A_.w;\
            PF[gg][4]=B_.x; PF[gg][5]=B_.y; PF[gg][6]=B_.z; PF[gg][7]=B_.w;\
        }                                                                  \
    }

#define PIPELINE(PARN)                                                     \
    {                                                                      \
        float sA = 0.f, sB = 0.f;                                          \
        _Pragma("unroll")                                                  \
        for (int k = 0; k < 8; ++k) { sA += hv[k]; sB += hv[k]*hv[k]; }    \
        sA = wave_allsum(sA); sB = wave_allsum(sB);                        \
        const float mu_ = sA * (1.f/512.f);                                \
        const float rs_ = rsqrtf(fmaxf(sB*(1.f/512.f) - mu_*mu_, 0.f)      \
                                 + EPSV);                                  \
        _Pragma("unroll")                                                  \
        for (int k = 0; k < 8; ++k)                                        \
            hgS[gu][wb[k]] = fmaf((hv[k]-mu_)*rs_, lnw[k], lnb[k]);        \
        float a_[8];                                                       \
        _Pragma("unroll") for (int k = 0; k < 8; ++k) a_[k] = 0.f;         \
        _Pragma("unroll")                                                  \
        for (int m = 0; m < 8; ++m) {                                      \
            const float xv = hgS[gu][rb2[m]];                              \
            _Pragma("unroll")                                              \
            for (int q = 0; q < 8; ++q)                                    \
                a_[q] = fmaf(xv, WA[m*8 + q], a_[q]);                      \
        }                                                                  \
        _Pragma("unroll")                                                  \
        for (int k = 0; k < 8; ++k) { T1S[gu][wb[k]] = a_[k]; a_[k] = 0.f;}\
        _Pragma("unroll")                                                  \
        for (int m = 0; m < 8; ++m) {                                      \
            const float xv2 = T1S[gu][rb2[m]];                             \
            _Pragma("unroll")                                              \
            for (int q = 0; q < 8; ++q)                                    \
                a_[q] = fmaf(xv2, WB[m*8 + q], a_[q]);                     \
        }                                                                  \
        _Pragma("unroll")                                                  \
        for (int k = 0; k < 8; ++k) { T2S[gu][wb[k]] = a_[k]; a_[k] = 0.f;}\
        _Pragma("unroll")                                                  \
        for (int m = 0; m < 8; ++m) {                                      \
            const float xv3 = T2S[gu][rb2[m]];                             \
            _Pragma("unroll")                                              \
            for (int q = 0; q < 8; ++q)                                    \
                a_[q] = fmaf(xv3, WC[m*8 + q], a_[q]);                     \
        }                                                                  \
        float sC = 0.f, sD = 0.f;                                          \
        _Pragma("unroll")                                                  \
        for (int k = 0; k < 8; ++k) {                                      \
            a_[k] += ubias[k]; sC += a_[k]; sD += a_[k]*a_[k];             \
        }                                                                  \
        sC = wave_allsum(sC); sD = wave_allsum(sD);                        \
        const float mu2_ = sC * (1.f/512.f);                               \
        const float rs2_ = rsqrtf(fmaxf(sD*(1.f/512.f) - mu2_*mu2_, 0.f)   \
                                  + EPSV);                                 \
        _Pragma("unroll")                                                  \
        for (int k = 0; k < 8; ++k) {                                      \
            uo[k] = fmaf((a_[k]-mu2_)*rs2_, low8[k], lob8[k]);             \
            UhS[PARN][gu][wb[k]] = uo[k];                                  \
        }                                                                  \
    }

#define COMBINE(PARC, PF, TT)                                              \
    {                                                                      \
        float ur[8], uz[8], un[8];                                         \
        if (gu == 0) {                                                     \
            _Pragma("unroll")                                              \
            for (int k = 0; k < 8; ++k) {                                  \
                ur[k] = uo[k];                                             \
                uz[k] = UhS[PARC][1][wb[k]];                               \
                un[k] = UhS[PARC][2][wb[k]];                               \
            }                                                              \
        } else if (gu == 1) {                                              \
            _Pragma("unroll")                                              \
            for (int k = 0; k < 8; ++k) {                                  \
                uz[k] = uo[k];                                             \
                ur[k] = UhS[PARC][0][wb[k]];                               \
                un[k] = UhS[PARC][2][wb[k]];                               \
            }                                                              \
        } else {                                                           \
            _Pragma("unroll")                                              \
            for (int k = 0; k < 8; ++k) {                                  \
                un[k] = uo[k];                                             \
                ur[k] = UhS[PARC][0][wb[k]];                               \
                uz[k] = UhS[PARC][1][wb[k]];                               \
            }                                                              \
        }                                                                  \
        _Pragma("unroll")                                                  \
        for (int k = 0; k < 8; ++k) {                                      \
            const float er_ = __expf(-(PF[0][k] + ur[k]));                 \
            const float r_  = __builtin_amdgcn_rcpf(1.f + er_);            \
            const float ez_ = __expf(-(PF[1][k] + uz[k]));                 \
            const float z_  = __builtin_amdgcn_rcpf(1.f + ez_);            \
            const float e2_ = __expf(2.f * (PF[2][k] + r_ * un[k]));       \
            const float nn_ = 1.f - 2.f*__builtin_amdgcn_rcpf(e2_ + 1.f);  \
            hv[k] = (1.f - z_)*nn_ + z_*hv[k];                             \
        }                                                                  \
        if (gu == 0) {                                                     \
            float* op_ = out + ((size_t)(TT) * B + n) * 512 + lane*8;      \
            *(float4*)op_     = make_float4(hv[0], hv[1], hv[2], hv[3]);   \
            *(float4*)(op_+4) = make_float4(hv[4], hv[5], hv[6], hv[7]);   \
        }                                                                  \
    }

    LOADWX(0, pfA);
    PIPELINE(0);                 // Uh(h0) -> parity 0 (+ uo for t=0)

    for (int t = 0; t < T; t += 2) {
        // ---------- even step: consume pfA / parity 0 ----------
        bar_lds();               // UhS[0] (all 3 planes) ready
        if (t + 1 < T) LOADWX(t + 1, pfB);   // in flight across barrier
        COMBINE(0, pfA, t)
        if (t + 1 < T) PIPELINE(1)           // Uh(h_{t+1}) -> parity 1
        // ---------- odd step: consume pfB / parity 1 ----------
        bar_lds();               // UhS[1] ready
        if (t + 2 < T) LOADWX(t + 2, pfA);
        COMBINE(1, pfB, t + 1)
        if (t + 2 < T) PIPELINE(0)           // Uh(h_{t+2}) -> parity 0
    }
#undef LOADWX
#undef PIPELINE
#undef COMBINE
}

extern "C" void kernel_launch(void* const* d_in, const int* in_sizes, int n_in,
                              void* d_out, int out_size, void* d_ws, size_t ws_size,
                              hipStream_t stream)
{
    const float* x    = (const float*)d_in[0];
    const float* h0   = (const float*)d_in[1];
    const float* Wfa  = (const float*)d_in[2];
    const float* Wfb  = (const float*)d_in[3];
    const float* Wfc  = (const float*)d_in[4];
    const float* Wba  = (const float*)d_in[5];
    const float* Wbb  = (const float*)d_in[6];
    const float* Wbc  = (const float*)d_in[7];
    const float* Wliw = (const float*)d_in[8];
    const float* Wlib = (const float*)d_in[9];
    const float* Wlow = (const float*)d_in[10];
    const float* Wlob = (const float*)d_in[11];
    const float* Ufa  = (const float*)d_in[12];
    const float* Ufb  = (const float*)d_in[13];
    const float* Ufc  = (const float*)d_in[14];
    const float* Uba  = (const float*)d_in[15];
    const float* Ubb  = (const float*)d_in[16];
    const float* Ubc  = (const float*)d_in[17];
    const float* Uliw = (const float*)d_in[18];
    const float* Ulib = (const float*)d_in[19];
    const float* Ulow = (const float*)d_in[20];
    const float* Ulob = (const float*)d_in[21];

    const int B = in_sizes[1] / 512;            // 16
    const int T = in_sizes[0] / (B * 4096);     // 512

    float* wxws = (float*)d_ws;                 // [T*B, 3, 512] scratch
    float* out  = (float*)d_out;

    wx_kernel<<<T * B, 256, 0, stream>>>(x, Wfa, Wfb, Wfc, Wba, Wbb, Wbc,
                                         Wliw, Wlib, Wlow, Wlob, wxws);
    scan_kernel<<<B, 192, 0, stream>>>(wxws, h0, Ufa, Ufb, Ufc, Uba, Ubb, Ubc,
                                       Uliw, Ulib, Ulow, Ulob, out, T, B);
}

// Round 8
// 915.562 us; speedup vs baseline: 1.1662x; 1.0394x over previous
//
#include <hip/hip_runtime.h>

#define EPSV 1e-5f

// DPP-based full-wave sum (verified correct rounds 2-7).
#define DPP_XADD(v, ctrl)                                                  \
    v += __int_as_float(__builtin_amdgcn_update_dpp(                       \
        0, __float_as_int(v), ctrl, 0xF, 0xF, false))

__device__ __forceinline__ float wave_allsum(float v) {
    DPP_XADD(v, 0x128);   // row_ror:8
    DPP_XADD(v, 0x124);   // row_ror:4
    DPP_XADD(v, 0x122);   // row_ror:2
    DPP_XADD(v, 0x121);   // row_ror:1
    DPP_XADD(v, 0x142);   // row_bcast15
    DPP_XADD(v, 0x143);   // row_bcast31
    return __int_as_float(__builtin_amdgcn_readlane(__float_as_int(v), 63));
}

// LDS-only barrier: waits own wave's DS ops then syncs; does not drain vmcnt.
__device__ __forceinline__ void bar_lds() {
    asm volatile("s_waitcnt lgkmcnt(0)\n\ts_barrier" ::: "memory");
}

// ============================================================
// Phase 1: input-to-hidden TCL3D (+LN in/out) for all (t,n).
// (unchanged from round 5 — verified)
// ============================================================
__global__ __launch_bounds__(256) void wx_kernel(
    const float* __restrict__ x,
    const float* __restrict__ Wfa, const float* __restrict__ Wfb,
    const float* __restrict__ Wfc,
    const float* __restrict__ Wba, const float* __restrict__ Wbb,
    const float* __restrict__ Wbc,
    const float* __restrict__ lniw, const float* __restrict__ lnib,
    const float* __restrict__ lnow, const float* __restrict__ lnob,
    float* __restrict__ wxo)
{
    __shared__ float Xs[4096];
    __shared__ float S1[2048];
    __shared__ float S2[1024];
    __shared__ float baS[24], bbS[24], bcS[24];
    __shared__ float red[16];

    const int tid  = threadIdx.x;
    const int wid  = tid >> 6, lane = tid & 63;
    const size_t tb = blockIdx.x;
    const float* xp = x + tb * 4096;

    float s = 0.f, s2 = 0.f;
    for (int i = tid; i < 4096; i += 256) {
        float v = xp[i];
        Xs[i] = v;
        s += v; s2 += v * v;
    }
    if (tid < 24) { baS[tid] = Wba[tid]; bbS[tid] = Wbb[tid]; bcS[tid] = Wbc[tid]; }

    __syncthreads();
    #pragma unroll
    for (int off = 32; off > 0; off >>= 1) {
        s  += __shfl_down(s,  off);
        s2 += __shfl_down(s2, off);
    }
    if (lane == 0) { red[wid] = s; red[8 + wid] = s2; }
    __syncthreads();
    s  = red[0] + red[1] + red[2] + red[3];
    s2 = red[8] + red[9] + red[10] + red[11];
    const float muX = s * (1.f / 4096.f);
    const float rsX = rsqrtf(fmaxf(s2 * (1.f / 4096.f) - muX * muX, 0.f) + EPSV);

    const int qh = __builtin_amdgcn_readfirstlane(tid >> 7);   // 0..1
    const int rh = __builtin_amdgcn_readfirstlane(tid >> 6);   // 0..3

    for (int g = 0; g < 3; ++g) {
        {
            float acc[8] = {0,0,0,0,0,0,0,0};
            const int rest = tid;                      // b*16+c
            const float* lw = lniw + g * 4096;
            const float* lb = lnib + g * 4096;
            #pragma unroll
            for (int m = 0; m < 16; ++m) {
                const float xn = (Xs[m*256 + rest] - muX) * rsX;
                const float xv = fmaf(xn, lw[m*256 + rest], lb[m*256 + rest]);
                #pragma unroll
                for (int p = 0; p < 8; ++p)
                    acc[p] = fmaf(xv, Wfa[(g*16 + m)*8 + p], acc[p]);
            }
            #pragma unroll
            for (int p = 0; p < 8; ++p)
                S1[p*256 + (rest ^ (p << 3))] = acc[p];
        }
        __syncthreads();
        {
            float acc[4] = {0,0,0,0};
            const int rest2 = tid & 127;               // c*8+p
            const int c2 = rest2 >> 3, p2 = rest2 & 7;
            #pragma unroll
            for (int m = 0; m < 16; ++m) {
                const float xv = S1[p2*256 + (((m << 4) | c2) ^ (p2 << 3))];
                #pragma unroll
                for (int j = 0; j < 4; ++j)
                    acc[j] = fmaf(xv, Wfb[(g*16 + m)*8 + qh*4 + j], acc[j]);
            }
            #pragma unroll
            for (int j = 0; j < 4; ++j) {
                const int q = qh*4 + j;
                S2[q*128 + (rest2 ^ (q << 3))] = acc[j];
            }
        }
        __syncthreads();
        float v0, v1; int idx0;
        {
            float acc[2] = {0, 0};
            const int rest3 = tid & 63;                // p*8+q
            const int q3 = rest3 & 7, pp = rest3 >> 3;
            #pragma unroll
            for (int m = 0; m < 16; ++m) {
                const float xv = S2[q3*128 + (((m << 3) | pp) ^ (q3 << 3))];
                #pragma unroll
                for (int j = 0; j < 2; ++j)
                    acc[j] = fmaf(xv, Wfc[(g*16 + m)*8 + rh*2 + j], acc[j]);
            }
            const float bpq = baS[g*8 + pp] * bbS[g*8 + q3];
            v0 = acc[0] + bpq * bcS[g*8 + rh*2 + 0];
            v1 = acc[1] + bpq * bcS[g*8 + rh*2 + 1];
            idx0 = rest3 * 8 + rh * 2;
        }
        float t = v0 + v1, t2 = v0*v0 + v1*v1;
        __syncthreads();
        #pragma unroll
        for (int off = 32; off > 0; off >>= 1) {
            t  += __shfl_down(t,  off);
            t2 += __shfl_down(t2, off);
        }
        if (lane == 0) { red[wid] = t; red[8 + wid] = t2; }
        __syncthreads();
        t  = red[0] + red[1] + red[2] + red[3];
        t2 = red[8] + red[9] + red[10] + red[11];
        const float mu  = t * (1.f / 512.f);
        const float var = fmaxf(t2 * (1.f / 512.f) - mu * mu, 0.f);
        const float rs  = rsqrtf(var + EPSV);
        float* wp = wxo + (tb * 3 + g) * 512;
        const float2 lw2 = *(const float2*)(lnow + g*512 + idx0);
        const float2 lb2 = *(const float2*)(lnob + g*512 + idx0);
        float2 o2;
        o2.x = fmaf((v0 - mu) * rs, lw2.x, lb2.x);
        o2.y = fmaf((v1 - mu) * rs, lw2.y, lb2.y);
        *(float2*)(wp + idx0) = o2;
    }
}

// ============================================================
// Phase 2: sequential GRU scan — R7 skeleton with PAD-72 LDS
// layout: phys(i) = (i&7)*72 + (i>>3).
//   writer (lane l, reg k): addr = k*72 + l   (stride-1/lanes,
//       lane-invariant delta 72 between k -> ds_write2_b32)
//   reader (lane l, m): addr = (l&7)*72 + m*8 + (l>>3)
//       (2-way banks, delta 8 between m -> ds_read2_b32)
// Halves DS instruction count vs the XOR scheme (72 -> 36 per
// wave per step). Everything else unchanged from R7.
// ============================================================
__global__ __launch_bounds__(192, 1) void scan_kernel(
    const float* __restrict__ wx,     // [T*B, 3, 512]
    const float* __restrict__ h0,     // [B, 512]
    const float* __restrict__ Ufa, const float* __restrict__ Ufb,
    const float* __restrict__ Ufc,
    const float* __restrict__ Uba, const float* __restrict__ Ubb,
    const float* __restrict__ Ubc,
    const float* __restrict__ lniw, const float* __restrict__ lnib,
    const float* __restrict__ lnow, const float* __restrict__ lnob,
    float* __restrict__ out,          // [T*B, 512]
    int T, int B)
{
    const int n    = blockIdx.x;
    const int tid  = threadIdx.x;
    const int lane = tid & 63;
    const int gu   = __builtin_amdgcn_readfirstlane(tid >> 6);  // wave = gate

    // 576 floats per plane (8 rows x 72)
    __shared__ float hgS[3][576];
    __shared__ float T1S[3][576];
    __shared__ float T2S[3][576];
    __shared__ float UhS[2][3][576];

    const float* __restrict__ WA = Ufa + gu * 64;   // uniform -> SMEM
    const float* __restrict__ WB = Ufb + gu * 64;
    const float* __restrict__ WC = Ufc + gu * 64;

    // ---- per-element coefficients (lane-varying, stay in VGPRs) ----
    float lnw[8], lnb[8], low8[8], lob8[8], ubias[8];
    {
        const int p_ = lane >> 3, q_ = lane & 7;
        const float bpq = Uba[gu*8 + p_] * Ubb[gu*8 + q_];
        #pragma unroll
        for (int k = 0; k < 8; ++k) {
            lnw[k]   = lniw[gu*512 + lane*8 + k];
            lnb[k]   = lnib[gu*512 + lane*8 + k];
            low8[k]  = lnow[gu*512 + lane*8 + k];
            lob8[k]  = lnob[gu*512 + lane*8 + k];
            ubias[k] = bpq * Ubc[gu*8 + k];
        }
    }

    // pad-72 addressing
    const int wbase = lane;                             // + k*72
    const int rbase = (lane & 7) * 72 + (lane >> 3);    // + m*8

    // ---- h in regs (element lane*8+k), redundant per wave ----
    float hv[8];
    {
        const float4 a = *(const float4*)(h0 + n*512 + lane*8);
        const float4 b = *(const float4*)(h0 + n*512 + lane*8 + 4);
        hv[0]=a.x; hv[1]=a.y; hv[2]=a.z; hv[3]=a.w;
        hv[4]=b.x; hv[5]=b.y; hv[6]=b.z; hv[7]=b.w;
    }

    float uo[8];                 // own gate's Uh (post-lnout)
    float pfA[3][8], pfB[3][8];  // wx prefetch, double-buffered

#define LOADWX(TT, PF)                                                     \
    {                                                                      \
        const float* base_ = wx + (((size_t)(TT) * B + n) * 3) * 512       \
                             + lane * 8;                                   \
        _Pragma("unroll")                                                  \
        for (int gg = 0; gg < 3; ++gg) {                                   \
            const float4 A_ = *(const float4*)(base_ + gg*512);            \
            const float4 B_ = *(const float4*)(base_ + gg*512 + 4);        \
            PF[gg][0]=A_.x; PF[gg][1]=A_.y; PF[gg][2]=A_.z; PF[gg][3]=A_.w;\
            PF[gg][4]=B_.x; PF[gg][5]=B_.y; PF[gg][6]=B_.z; PF[gg][7]=B_.w;\
        }                                                                  \
    }

    // paired write: k=0..3 from p0 (byte offs 0/288/576/864),
    // k=4..7 from p1 = p0+288 floats -> same offsets. All merge to write2.
#define WR8(BUFROW, V)                                                     \
    {                                                                      \
        float* p0_ = (BUFROW) + wbase;                                     \
        float* p1_ = p0_ + 288;                                            \
        p0_[0] = V[0]; p0_[72] = V[1]; p0_[144] = V[2]; p0_[216] = V[3];   \
        p1_[0] = V[4]; p1_[72] = V[5]; p1_[144] = V[6]; p1_[216] = V[7];   \
    }

#define RD8(BUFROW, V)                                                     \
    {                                                                      \
        const float* q_ = (BUFROW) + rbase;                                \
        V[0] = q_[0];  V[1] = q_[8];  V[2] = q_[16]; V[3] = q_[24];        \
        V[4] = q_[32]; V[5] = q_[40]; V[6] = q_[48]; V[7] = q_[56];        \
    }

    // read own-layout (writer-pattern) values from a plane (COMBINE)
#define RD8W(BUFROW, V)                                                    \
    {                                                                      \
        const float* q0_ = (BUFROW) + wbase;                               \
        const float* q1_ = q0_ + 288;                                      \
        V[0] = q0_[0]; V[1] = q0_[72]; V[2] = q0_[144]; V[3] = q0_[216];   \
        V[4] = q1_[0]; V[5] = q1_[72]; V[6] = q1_[144]; V[7] = q1_[216];   \
    }

#define PIPELINE(PARN)                                                     \
    {                                                                      \
        float sA = 0.f, sB = 0.f;                                          \
        _Pragma("unroll")                                                  \
        for (int k = 0; k < 8; ++k) { sA += hv[k]; sB += hv[k]*hv[k]; }    \
        sA = wave_allsum(sA); sB = wave_allsum(sB);                        \
        const float mu_ = sA * (1.f/512.f);                                \
        const float rs_ = rsqrtf(fmaxf(sB*(1.f/512.f) - mu_*mu_, 0.f)      \
                                 + EPSV);                                  \
        float hg_[8];                                                      \
        _Pragma("unroll")                                                  \
        for (int k = 0; k < 8; ++k)                                        \
            hg_[k] = fmaf((hv[k]-mu_)*rs_, lnw[k], lnb[k]);                \
        WR8(hgS[gu], hg_)                                                  \
        float xv_[8], a_[8];                                               \
        _Pragma("unroll") for (int k = 0; k < 8; ++k) a_[k] = 0.f;         \
        RD8(hgS[gu], xv_)                                                  \
        _Pragma("unroll")                                                  \
        for (int m = 0; m < 8; ++m)                                        \
            _Pragma("unroll")                                              \
            for (int q = 0; q < 8; ++q)                                    \
                a_[q] = fmaf(xv_[m], WA[m*8 + q], a_[q]);                  \
        WR8(T1S[gu], a_)                                                   \
        RD8(T1S[gu], xv_)                                                  \
        _Pragma("unroll") for (int k = 0; k < 8; ++k) a_[k] = 0.f;         \
        _Pragma("unroll")                                                  \
        for (int m = 0; m < 8; ++m)                                        \
            _Pragma("unroll")                                              \
            for (int q = 0; q < 8; ++q)                                    \
                a_[q] = fmaf(xv_[m], WB[m*8 + q], a_[q]);                  \
        WR8(T2S[gu], a_)                                                   \
        RD8(T2S[gu], xv_)                                                  \
        _Pragma("unroll") for (int k = 0; k < 8; ++k) a_[k] = 0.f;         \
        _Pragma("unroll")                                                  \
        for (int m = 0; m < 8; ++m)                                        \
            _Pragma("unroll")                                              \
            for (int q = 0; q < 8; ++q)                                    \
                a_[q] = fmaf(xv_[m], WC[m*8 + q], a_[q]);                  \
        float sC = 0.f, sD = 0.f;                                          \
        _Pragma("unroll")                                                  \
        for (int k = 0; k < 8; ++k) {                                      \
            a_[k] += ubias[k]; sC += a_[k]; sD += a_[k]*a_[k];             \
        }                                                                  \
        sC = wave_allsum(sC); sD = wave_allsum(sD);                        \
        const float mu2_ = sC * (1.f/512.f);                               \
        const float rs2_ = rsqrtf(fmaxf(sD*(1.f/512.f) - mu2_*mu2_, 0.f)   \
                                  + EPSV);                                 \
        _Pragma("unroll")                                                  \
        for (int k = 0; k < 8; ++k)                                        \
            uo[k] = fmaf((a_[k]-mu2_)*rs2_, low8[k], lob8[k]);             \
        WR8(UhS[PARN][gu], uo)                                             \
    }

#define COMBINE(PARC, PF, TT)                                              \
    {                                                                      \
        float ur[8], uz[8], un[8];                                         \
        if (gu == 0) {                                                     \
            _Pragma("unroll")                                              \
            for (int k = 0; k < 8; ++k) ur[k] = uo[k];                     \
            RD8W(UhS[PARC][1], uz)                                         \
            RD8W(UhS[PARC][2], un)                                         \
        } else if (gu == 1) {                                              \
            _Pragma("unroll")                                              \
            for (int k = 0; k < 8; ++k) uz[k] = uo[k];                     \
            RD8W(UhS[PARC][0], ur)                                         \
            RD8W(UhS[PARC][2], un)                                         \
        } else {                                                           \
            _Pragma("unroll")                                              \
            for (int k = 0; k < 8; ++k) un[k] = uo[k];                     \
            RD8W(UhS[PARC][0], ur)                                         \
            RD8W(UhS[PARC][1], uz)                                         \
        }                                                                  \
        _Pragma("unroll")                                                  \
        for (int k = 0; k < 8; ++k) {                                      \
            const float er_ = __expf(-(PF[0][k] + ur[k]));                 \
            const float r_  = __builtin_amdgcn_rcpf(1.f + er_);            \
            const float ez_ = __expf(-(PF[1][k] + uz[k]));                 \
            const float z_  = __builtin_amdgcn_rcpf(1.f + ez_);            \
            const float e2_ = __expf(2.f * (PF[2][k] + r_ * un[k]));       \
            const float nn_ = 1.f - 2.f*__builtin_amdgcn_rcpf(e2_ + 1.f);  \
            hv[k] = (1.f - z_)*nn_ + z_*hv[k];                             \
        }                                                                  \
        if (gu == 0) {                                                     \
            float* op_ = out + ((size_t)(TT) * B + n) * 512 + lane*8;      \
            *(float4*)op_     = make_float4(hv[0], hv[1], hv[2], hv[3]);   \
            *(float4*)(op_+4) = make_float4(hv[4], hv[5], hv[6], hv[7]);   \
        }                                                                  \
    }

    LOADWX(0, pfA);
    PIPELINE(0);                 // Uh(h0) -> parity 0 (+ uo for t=0)

    for (int t = 0; t < T; t += 2) {
        // ---------- even step: consume pfA / parity 0 ----------
        bar_lds();               // UhS[0] (all 3 planes) ready
        if (t + 1 < T) LOADWX(t + 1, pfB);   // stays in flight across barrier
        COMBINE(0, pfA, t)
        if (t + 1 < T) PIPELINE(1)           // Uh(h_{t+1}) -> parity 1
        // ---------- odd step: consume pfB / parity 1 ----------
        bar_lds();               // UhS[1] ready
        if (t + 2 < T) LOADWX(t + 2, pfA);
        COMBINE(1, pfB, t + 1)
        if (t + 2 < T) PIPELINE(0)           // Uh(h_{t+2}) -> parity 0
    }
#undef LOADWX
#undef WR8
#undef RD8
#undef RD8W
#undef PIPELINE
#undef COMBINE
}

extern "C" void kernel_launch(void* const* d_in, const int* in_sizes, int n_in,
                              void* d_out, int out_size, void* d_ws, size_t ws_size,
                              hipStream_t stream)
{
    const float* x    = (const float*)d_in[0];
    const float* h0   = (const float*)d_in[1];
    const float* Wfa  = (const float*)d_in[2];
    const float* Wfb  = (const float*)d_in[3];
    const float* Wfc  = (const float*)d_in[4];
    const float* Wba  = (const float*)d_in[5];
    const float* Wbb  = (const float*)d_in[6];
    const float* Wbc  = (const float*)d_in[7];
    const float* Wliw = (const float*)d_in[8];
    const float* Wlib = (const float*)d_in[9];
    const float* Wlow = (const float*)d_in[10];
    const float* Wlob = (const float*)d_in[11];
    const float* Ufa  = (const float*)d_in[12];
    const float* Ufb  = (const float*)d_in[13];
    const float* Ufc  = (const float*)d_in[14];
    const float* Uba  = (const float*)d_in[15];
    const float* Ubb  = (const float*)d_in[16];
    const float* Ubc  = (const float*)d_in[17];
    const float* Uliw = (const float*)d_in[18];
    const float* Ulib = (const float*)d_in[19];
    const float* Ulow = (const float*)d_in[20];
    const float* Ulob = (const float*)d_in[21];

    const int B = in_sizes[1] / 512;            // 16
    const int T = in_sizes[0] / (B * 4096);     // 512

    float* wxws = (float*)d_ws;                 // [T*B, 3, 512] scratch
    float* out  = (float*)d_out;

    wx_kernel<<<T * B, 256, 0, stream>>>(x, Wfa, Wfb, Wfc, Wba, Wbb, Wbc,
                                         Wliw, Wlib, Wlow, Wlob, wxws);
    scan_kernel<<<B, 192, 0, stream>>>(wxws, h0, Ufa, Ufb, Ufc, Uba, Ubb, Ubc,
                                       Uliw, Ulib, Ulow, Ulob, out, T, B);
}

// Round 9
// 812.212 us; speedup vs baseline: 1.3146x; 1.1272x over previous
//
#include <hip/hip_runtime.h>

#define EPSV 1e-5f

#define KEEPV(x) asm volatile("" : "+v"(x))
#define KEEPS(x) asm volatile("" : "+s"(x))

// DPP-based full-wave sum (verified correct rounds 2-8).
#define DPP_XADD(v, ctrl)                                                  \
    v += __int_as_float(__builtin_amdgcn_update_dpp(                       \
        0, __float_as_int(v), ctrl, 0xF, 0xF, false))

__device__ __forceinline__ float wave_allsum(float v) {
    DPP_XADD(v, 0x128);   // row_ror:8
    DPP_XADD(v, 0x124);   // row_ror:4
    DPP_XADD(v, 0x122);   // row_ror:2
    DPP_XADD(v, 0x121);   // row_ror:1
    DPP_XADD(v, 0x142);   // row_bcast15
    DPP_XADD(v, 0x143);   // row_bcast31
    return __int_as_float(__builtin_amdgcn_readlane(__float_as_int(v), 63));
}

// LDS-only barrier: waits own wave's DS ops then syncs; does not drain vmcnt.
__device__ __forceinline__ void bar_lds() {
    asm volatile("s_waitcnt lgkmcnt(0)\n\ts_barrier" ::: "memory");
}

// ============================================================
// Phase 1: input-to-hidden TCL3D (+LN in/out) for all (t,n).
// (unchanged from round 5 — verified)
// ============================================================
__global__ __launch_bounds__(256) void wx_kernel(
    const float* __restrict__ x,
    const float* __restrict__ Wfa, const float* __restrict__ Wfb,
    const float* __restrict__ Wfc,
    const float* __restrict__ Wba, const float* __restrict__ Wbb,
    const float* __restrict__ Wbc,
    const float* __restrict__ lniw, const float* __restrict__ lnib,
    const float* __restrict__ lnow, const float* __restrict__ lnob,
    float* __restrict__ wxo)
{
    __shared__ float Xs[4096];
    __shared__ float S1[2048];
    __shared__ float S2[1024];
    __shared__ float baS[24], bbS[24], bcS[24];
    __shared__ float red[16];

    const int tid  = threadIdx.x;
    const int wid  = tid >> 6, lane = tid & 63;
    const size_t tb = blockIdx.x;
    const float* xp = x + tb * 4096;

    float s = 0.f, s2 = 0.f;
    for (int i = tid; i < 4096; i += 256) {
        float v = xp[i];
        Xs[i] = v;
        s += v; s2 += v * v;
    }
    if (tid < 24) { baS[tid] = Wba[tid]; bbS[tid] = Wbb[tid]; bcS[tid] = Wbc[tid]; }

    __syncthreads();
    #pragma unroll
    for (int off = 32; off > 0; off >>= 1) {
        s  += __shfl_down(s,  off);
        s2 += __shfl_down(s2, off);
    }
    if (lane == 0) { red[wid] = s; red[8 + wid] = s2; }
    __syncthreads();
    s  = red[0] + red[1] + red[2] + red[3];
    s2 = red[8] + red[9] + red[10] + red[11];
    const float muX = s * (1.f / 4096.f);
    const float rsX = rsqrtf(fmaxf(s2 * (1.f / 4096.f) - muX * muX, 0.f) + EPSV);

    const int qh = __builtin_amdgcn_readfirstlane(tid >> 7);   // 0..1
    const int rh = __builtin_amdgcn_readfirstlane(tid >> 6);   // 0..3

    for (int g = 0; g < 3; ++g) {
        {
            float acc[8] = {0,0,0,0,0,0,0,0};
            const int rest = tid;                      // b*16+c
            const float* lw = lniw + g * 4096;
            const float* lb = lnib + g * 4096;
            #pragma unroll
            for (int m = 0; m < 16; ++m) {
                const float xn = (Xs[m*256 + rest] - muX) * rsX;
                const float xv = fmaf(xn, lw[m*256 + rest], lb[m*256 + rest]);
                #pragma unroll
                for (int p = 0; p < 8; ++p)
                    acc[p] = fmaf(xv, Wfa[(g*16 + m)*8 + p], acc[p]);
            }
            #pragma unroll
            for (int p = 0; p < 8; ++p)
                S1[p*256 + (rest ^ (p << 3))] = acc[p];
        }
        __syncthreads();
        {
            float acc[4] = {0,0,0,0};
            const int rest2 = tid & 127;               // c*8+p
            const int c2 = rest2 >> 3, p2 = rest2 & 7;
            #pragma unroll
            for (int m = 0; m < 16; ++m) {
                const float xv = S1[p2*256 + (((m << 4) | c2) ^ (p2 << 3))];
                #pragma unroll
                for (int j = 0; j < 4; ++j)
                    acc[j] = fmaf(xv, Wfb[(g*16 + m)*8 + qh*4 + j], acc[j]);
            }
            #pragma unroll
            for (int j = 0; j < 4; ++j) {
                const int q = qh*4 + j;
                S2[q*128 + (rest2 ^ (q << 3))] = acc[j];
            }
        }
        __syncthreads();
        float v0, v1; int idx0;
        {
            float acc[2] = {0, 0};
            const int rest3 = tid & 63;                // p*8+q
            const int q3 = rest3 & 7, pp = rest3 >> 3;
            #pragma unroll
            for (int m = 0; m < 16; ++m) {
                const float xv = S2[q3*128 + (((m << 3) | pp) ^ (q3 << 3))];
                #pragma unroll
                for (int j = 0; j < 2; ++j)
                    acc[j] = fmaf(xv, Wfc[(g*16 + m)*8 + rh*2 + j], acc[j]);
            }
            const float bpq = baS[g*8 + pp] * bbS[g*8 + q3];
            v0 = acc[0] + bpq * bcS[g*8 + rh*2 + 0];
            v1 = acc[1] + bpq * bcS[g*8 + rh*2 + 1];
            idx0 = rest3 * 8 + rh * 2;
        }
        float t = v0 + v1, t2 = v0*v0 + v1*v1;
        __syncthreads();
        #pragma unroll
        for (int off = 32; off > 0; off >>= 1) {
            t  += __shfl_down(t,  off);
            t2 += __shfl_down(t2, off);
        }
        if (lane == 0) { red[wid] = t; red[8 + wid] = t2; }
        __syncthreads();
        t  = red[0] + red[1] + red[2] + red[3];
        t2 = red[8] + red[9] + red[10] + red[11];
        const float mu  = t * (1.f / 512.f);
        const float var = fmaxf(t2 * (1.f / 512.f) - mu * mu, 0.f);
        const float rs  = rsqrtf(var + EPSV);
        float* wp = wxo + (tb * 3 + g) * 512;
        const float2 lw2 = *(const float2*)(lnow + g*512 + idx0);
        const float2 lb2 = *(const float2*)(lnob + g*512 + idx0);
        float2 o2;
        o2.x = fmaf((v0 - mu) * rs, lw2.x, lb2.x);
        o2.y = fmaf((v1 - mu) * rs, lw2.y, lb2.y);
        *(float2*)(wp + idx0) = o2;
    }
}

// ============================================================
// Phase 2: sequential GRU scan — R8 skeleton (pad-72 LDS,
// LDS-only barrier, h/uo in regs) with ALL U-factor weights
// preloaded into registers BEFORE the t-loop:
//   stage A -> 64 SGPRs (readfirstlane, "+s"-pinned)
//   stages B/C -> 128 VGPRs ("+v"-pinned)
// In-loop lgkmcnt tracks DS only -> turnaround waits are
// ~40cy instead of draining ~200cy out-of-order SMEM loads.
// Single pf buffer (loads issued post-COMBINE, consumed after
// next barrier — a full PIPELINE of slack, never drained).
// ============================================================
__global__ __launch_bounds__(192, 1) void scan_kernel(
    const float* __restrict__ wx,     // [T*B, 3, 512]
    const float* __restrict__ h0,     // [B, 512]
    const float* __restrict__ Ufa, const float* __restrict__ Ufb,
    const float* __restrict__ Ufc,
    const float* __restrict__ Uba, const float* __restrict__ Ubb,
    const float* __restrict__ Ubc,
    const float* __restrict__ lniw, const float* __restrict__ lnib,
    const float* __restrict__ lnow, const float* __restrict__ lnob,
    float* __restrict__ out,          // [T*B, 512]
    int T, int B)
{
    const int n    = blockIdx.x;
    const int tid  = threadIdx.x;
    const int lane = tid & 63;
    const int gu   = __builtin_amdgcn_readfirstlane(tid >> 6);  // wave = gate

    // 576 floats per plane (8 rows x 72)
    __shared__ float hgS[3][576];
    __shared__ float T1S[3][576];
    __shared__ float T2S[3][576];
    __shared__ float UhS[2][3][576];

    // ---- preload ALL weights into registers (once, pre-loop) ----
    float wA[64], wB[64], wC[64];
    #pragma unroll
    for (int i = 0; i < 64; ++i) {
        wA[i] = __uint_as_float(__builtin_amdgcn_readfirstlane(
                    __float_as_uint(Ufa[gu*64 + i])));
        KEEPS(wA[i]);
    }
    #pragma unroll
    for (int i = 0; i < 64; ++i) { wB[i] = Ufb[gu*64 + i]; KEEPV(wB[i]); }
    #pragma unroll
    for (int i = 0; i < 64; ++i) { wC[i] = Ufc[gu*64 + i]; KEEPV(wC[i]); }

    // ---- per-element coefficients (lane-varying, stay in VGPRs) ----
    float lnw[8], lnb[8], low8[8], lob8[8], ubias[8];
    {
        const int p_ = lane >> 3, q_ = lane & 7;
        const float bpq = Uba[gu*8 + p_] * Ubb[gu*8 + q_];
        #pragma unroll
        for (int k = 0; k < 8; ++k) {
            lnw[k]   = lniw[gu*512 + lane*8 + k];
            lnb[k]   = lnib[gu*512 + lane*8 + k];
            low8[k]  = lnow[gu*512 + lane*8 + k];
            lob8[k]  = lnob[gu*512 + lane*8 + k];
            ubias[k] = bpq * Ubc[gu*8 + k];
        }
    }

    // pad-72 addressing (verified R8)
    const int wbase = lane;                             // + k*72
    const int rbase = (lane & 7) * 72 + (lane >> 3);    // + m*8

    // ---- h in regs (element lane*8+k), redundant per wave ----
    float hv[8];
    {
        const float4 a = *(const float4*)(h0 + n*512 + lane*8);
        const float4 b = *(const float4*)(h0 + n*512 + lane*8 + 4);
        hv[0]=a.x; hv[1]=a.y; hv[2]=a.z; hv[3]=a.w;
        hv[4]=b.x; hv[5]=b.y; hv[6]=b.z; hv[7]=b.w;
    }

    float uo[8];        // own gate's Uh (post-lnout)
    float pf[3][8];     // wx prefetch (single buffer)

#define LOADWX(TT)                                                         \
    {                                                                      \
        const float* base_ = wx + (((size_t)(TT) * B + n) * 3) * 512       \
                             + lane * 8;                                   \
        _Pragma("unroll")                                                  \
        for (int gg = 0; gg < 3; ++gg) {                                   \
            const float4 A_ = *(const float4*)(base_ + gg*512);            \
            const float4 B_ = *(const float4*)(base_ + gg*512 + 4);        \
            pf[gg][0]=A_.x; pf[gg][1]=A_.y; pf[gg][2]=A_.z; pf[gg][3]=A_.w;\
            pf[gg][4]=B_.x; pf[gg][5]=B_.y; pf[gg][6]=B_.z; pf[gg][7]=B_.w;\
        }                                                                  \
    }

#define WR8(BUFROW, V)                                                     \
    {                                                                      \
        float* p0_ = (BUFROW) + wbase;                                     \
        float* p1_ = p0_ + 288;                                            \
        p0_[0] = V[0]; p0_[72] = V[1]; p0_[144] = V[2]; p0_[216] = V[3];   \
        p1_[0] = V[4]; p1_[72] = V[5]; p1_[144] = V[6]; p1_[216] = V[7];   \
    }

#define RD8(BUFROW, V)                                                     \
    {                                                                      \
        const float* q_ = (BUFROW) + rbase;                                \
        V[0] = q_[0];  V[1] = q_[8];  V[2] = q_[16]; V[3] = q_[24];        \
        V[4] = q_[32]; V[5] = q_[40]; V[6] = q_[48]; V[7] = q_[56];        \
    }

#define RD8W(BUFROW, V)                                                    \
    {                                                                      \
        const float* q0_ = (BUFROW) + wbase;                               \
        const float* q1_ = q0_ + 288;                                      \
        V[0] = q0_[0]; V[1] = q0_[72]; V[2] = q0_[144]; V[3] = q0_[216];   \
        V[4] = q1_[0]; V[5] = q1_[72]; V[6] = q1_[144]; V[7] = q1_[216];   \
    }

#define PIPELINE(PARN)                                                     \
    {                                                                      \
        float sA = 0.f, sB = 0.f;                                          \
        _Pragma("unroll")                                                  \
        for (int k = 0; k < 8; ++k) { sA += hv[k]; sB += hv[k]*hv[k]; }    \
        sA = wave_allsum(sA); sB = wave_allsum(sB);                        \
        const float mu_ = sA * (1.f/512.f);                                \
        const float rs_ = rsqrtf(fmaxf(sB*(1.f/512.f) - mu_*mu_, 0.f)      \
                                 + EPSV);                                  \
        float hg_[8];                                                      \
        _Pragma("unroll")                                                  \
        for (int k = 0; k < 8; ++k)                                        \
            hg_[k] = fmaf((hv[k]-mu_)*rs_, lnw[k], lnb[k]);                \
        WR8(hgS[gu], hg_)                                                  \
        float xv_[8], a_[8];                                               \
        _Pragma("unroll") for (int k = 0; k < 8; ++k) a_[k] = 0.f;         \
        RD8(hgS[gu], xv_)                                                  \
        _Pragma("unroll")                                                  \
        for (int m = 0; m < 8; ++m)                                        \
            _Pragma("unroll")                                              \
            for (int q = 0; q < 8; ++q)                                    \
                a_[q] = fmaf(xv_[m], wA[m*8 + q], a_[q]);                  \
        WR8(T1S[gu], a_)                                                   \
        RD8(T1S[gu], xv_)                                                  \
        _Pragma("unroll") for (int k = 0; k < 8; ++k) a_[k] = 0.f;         \
        _Pragma("unroll")                                                  \
        for (int m = 0; m < 8; ++m)                                        \
            _Pragma("unroll")                                              \
            for (int q = 0; q < 8; ++q)                                    \
                a_[q] = fmaf(xv_[m], wB[m*8 + q], a_[q]);                  \
        WR8(T2S[gu], a_)                                                   \
        RD8(T2S[gu], xv_)                                                  \
        _Pragma("unroll") for (int k = 0; k < 8; ++k) a_[k] = 0.f;         \
        _Pragma("unroll")                                                  \
        for (int m = 0; m < 8; ++m)                                        \
            _Pragma("unroll")                                              \
            for (int q = 0; q < 8; ++q)                                    \
                a_[q] = fmaf(xv_[m], wC[m*8 + q], a_[q]);                  \
        float sC = 0.f, sD = 0.f;                                          \
        _Pragma("unroll")                                                  \
        for (int k = 0; k < 8; ++k) {                                      \
            a_[k] += ubias[k]; sC += a_[k]; sD += a_[k]*a_[k];             \
        }                                                                  \
        sC = wave_allsum(sC); sD = wave_allsum(sD);                        \
        const float mu2_ = sC * (1.f/512.f);                               \
        const float rs2_ = rsqrtf(fmaxf(sD*(1.f/512.f) - mu2_*mu2_, 0.f)   \
                                  + EPSV);                                 \
        _Pragma("unroll")                                                  \
        for (int k = 0; k < 8; ++k)                                        \
            uo[k] = fmaf((a_[k]-mu2_)*rs2_, low8[k], lob8[k]);             \
        WR8(UhS[PARN][gu], uo)                                             \
    }

#define COMBINE(PARC, TT)                                                  \
    {                                                                      \
        float ur[8], uz[8], un[8];                                         \
        if (gu == 0) {                                                     \
            _Pragma("unroll")                                              \
            for (int k = 0; k < 8; ++k) ur[k] = uo[k];                     \
            RD8W(UhS[PARC][1], uz)                                         \
            RD8W(UhS[PARC][2], un)                                         \
        } else if (gu == 1) {                                              \
            _Pragma("unroll")                                              \
            for (int k = 0; k < 8; ++k) uz[k] = uo[k];                     \
            RD8W(UhS[PARC][0], ur)                                         \
            RD8W(UhS[PARC][2], un)                                         \
        } else {                                                           \
            _Pragma("unroll")                                              \
            for (int k = 0; k < 8; ++k) un[k] = uo[k];                     \
            RD8W(UhS[PARC][0], ur)                                         \
            RD8W(UhS[PARC][1], uz)                                         \
        }                                                                  \
        _Pragma("unroll")                                                  \
        for (int k = 0; k < 8; ++k) {                                      \
            const float er_ = __expf(-(pf[0][k] + ur[k]));                 \
            const float r_  = __builtin_amdgcn_rcpf(1.f + er_);            \
            const float ez_ = __expf(-(pf[1][k] + uz[k]));                 \
            const float z_  = __builtin_amdgcn_rcpf(1.f + ez_);            \
            const float e2_ = __expf(2.f * (pf[2][k] + r_ * un[k]));       \
            const float nn_ = 1.f - 2.f*__builtin_amdgcn_rcpf(e2_ + 1.f);  \
            hv[k] = (1.f - z_)*nn_ + z_*hv[k];                             \
        }                                                                  \
        if (gu == 0) {                                                     \
            float* op_ = out + ((size_t)(TT) * B + n) * 512 + lane*8;      \
            *(float4*)op_     = make_float4(hv[0], hv[1], hv[2], hv[3]);   \
            *(float4*)(op_+4) = make_float4(hv[4], hv[5], hv[6], hv[7]);   \
        }                                                                  \
    }

    LOADWX(0);
    PIPELINE(0);                 // Uh(h0) -> parity 0 (+ uo for t=0)

    for (int t = 0; t < T; t += 2) {
        // ---------- even step ----------
        bar_lds();               // UhS[0] (all 3 planes) ready
        COMBINE(0, t)
        if (t + 1 < T) {
            LOADWX(t + 1);       // issued here, consumed after next barrier
            PIPELINE(1)          // Uh(h_{t+1}) -> parity 1
        }
        // ---------- odd step ----------
        bar_lds();               // UhS[1] ready
        if (t + 1 < T) COMBINE(1, t + 1)
        if (t + 2 < T) {
            LOADWX(t + 2);
            PIPELINE(0)          // Uh(h_{t+2}) -> parity 0
        }
    }
#undef LOADWX
#undef WR8
#undef RD8
#undef RD8W
#undef PIPELINE
#undef COMBINE
}

extern "C" void kernel_launch(void* const* d_in, const int* in_sizes, int n_in,
                              void* d_out, int out_size, void* d_ws, size_t ws_size,
                              hipStream_t stream)
{
    const float* x    = (const float*)d_in[0];
    const float* h0   = (const float*)d_in[1];
    const float* Wfa  = (const float*)d_in[2];
    const float* Wfb  = (const float*)d_in[3];
    const float* Wfc  = (const float*)d_in[4];
    const float* Wba  = (const float*)d_in[5];
    const float* Wbb  = (const float*)d_in[6];
    const float* Wbc  = (const float*)d_in[7];
    const float* Wliw = (const float*)d_in[8];
    const float* Wlib = (const float*)d_in[9];
    const float* Wlow = (const float*)d_in[10];
    const float* Wlob = (const float*)d_in[11];
    const float* Ufa  = (const float*)d_in[12];
    const float* Ufb  = (const float*)d_in[13];
    const float* Ufc  = (const float*)d_in[14];
    const float* Uba  = (const float*)d_in[15];
    const float* Ubb  = (const float*)d_in[16];
    const float* Ubc  = (const float*)d_in[17];
    const float* Uliw = (const float*)d_in[18];
    const float* Ulib = (const float*)d_in[19];
    const float* Ulow = (const float*)d_in[20];
    const float* Ulob = (const float*)d_in[21];

    const int B = in_sizes[1] / 512;            // 16
    const int T = in_sizes[0] / (B * 4096);     // 512

    float* wxws = (float*)d_ws;                 // [T*B, 3, 512] scratch
    float* out  = (float*)d_out;

    wx_kernel<<<T * B, 256, 0, stream>>>(x, Wfa, Wfb, Wfc, Wba, Wbb, Wbc,
                                         Wliw, Wlib, Wlow, Wlob, wxws);
    scan_kernel<<<B, 192, 0, stream>>>(wxws, h0, Ufa, Ufb, Ufc, Uba, Ubb, Ubc,
                                       Uliw, Ulib, Ulow, Ulob, out, T, B);
}